// Round 21
// baseline (150.683 us; speedup 1.0000x reference)
//
#include <hip/hip_runtime.h>
#include <math.h>

#define Bn 4
#define Cn 32
#define Dn 64
#define Hn 64
#define Wn 64
#define HW (Hn * Wn)
#define DHW (Dn * Hn * Wn)      /* 262144 */
#define TOT (Bn * Cn * DHW)     /* 33554432 */
#define NCHUNK 128              /* spatial chunks per batch in reduce */
#define NWH 1372                /* 4*7*7*7 half2 weights */

typedef float f4 __attribute__((ext_vector_type(4)));
typedef unsigned int u32;
typedef u32 u4 __attribute__((ext_vector_type(4)));
typedef _Float16 h2 __attribute__((ext_vector_type(2)));

__device__ __forceinline__ u32 packh2(float a, float b) {
    h2 h;
    h.x = (_Float16)a;
    h.y = (_Float16)b;
    return __builtin_bit_cast(u32, h);
}
__device__ __forceinline__ h2 uash2(u32 u) { return __builtin_bit_cast(h2, u); }

__device__ __forceinline__ float dot2acc(u32 iv, u32 wv, float acc) {
#if __has_builtin(__builtin_amdgcn_fdot2)
    return __builtin_amdgcn_fdot2(uash2(iv), uash2(wv), acc, false);
#else
    const h2 a = uash2(iv), b = uash2(wv);
    return acc + (float)a.x * (float)b.x + (float)a.y * (float)b.y;
#endif
}

// ============================================================
// Kernel 1: fused reductions — R20 (measured-good). UNCHANGED.
// Spatial stats stored as interleaved half2(avg,max); partials fp32.
// ============================================================
__global__ __launch_bounds__(256) void reduce_kernel(
    const float* __restrict__ x, u32* __restrict__ s_am,
    float* __restrict__ part_sum, float* __restrict__ part_max) {
    const int b = blockIdx.x / NCHUNK;
    const int chunk = blockIdx.x % NCHUNK;
    const int base = chunk * 2048 + threadIdx.x * 4;
    const int lane = threadIdx.x & 63;
    const int wid = threadIdx.x >> 6;

    f4 ssum0 = {0.f, 0.f, 0.f, 0.f}, ssum1 = {0.f, 0.f, 0.f, 0.f};
    f4 smax0 = {-INFINITY, -INFINITY, -INFINITY, -INFINITY};
    f4 smax1 = smax0;
    float tsum[Cn], tmax[Cn];

    const float* xp = x + (size_t)b * Cn * DHW + base;
#pragma unroll
    for (int c = 0; c < Cn; ++c) {
        const f4 v0 = *reinterpret_cast<const f4*>(xp + (size_t)c * DHW);
        const f4 v1 = *reinterpret_cast<const f4*>(xp + (size_t)c * DHW + 1024);
        ssum0 += v0; ssum1 += v1;
        smax0.x = fmaxf(smax0.x, v0.x); smax0.y = fmaxf(smax0.y, v0.y);
        smax0.z = fmaxf(smax0.z, v0.z); smax0.w = fmaxf(smax0.w, v0.w);
        smax1.x = fmaxf(smax1.x, v1.x); smax1.y = fmaxf(smax1.y, v1.y);
        smax1.z = fmaxf(smax1.z, v1.z); smax1.w = fmaxf(smax1.w, v1.w);
        const float s0 = (v0.x + v0.y) + (v0.z + v0.w);
        const float s1 = (v1.x + v1.y) + (v1.z + v1.w);
        tsum[c] = s0 + s1;
        const float m0 = fmaxf(fmaxf(v0.x, v0.y), fmaxf(v0.z, v0.w));
        const float m1 = fmaxf(fmaxf(v1.x, v1.y), fmaxf(v1.z, v1.w));
        tmax[c] = fmaxf(m0, m1);
    }

    const f4 av0 = ssum0 * (1.f / Cn);
    const f4 av1 = ssum1 * (1.f / Cn);
    u4 o0 = {packh2(av0.x, smax0.x), packh2(av0.y, smax0.y),
             packh2(av0.z, smax0.z), packh2(av0.w, smax0.w)};
    u4 o1 = {packh2(av1.x, smax1.x), packh2(av1.y, smax1.y),
             packh2(av1.z, smax1.z), packh2(av1.w, smax1.w)};
    *reinterpret_cast<u4*>(s_am + (size_t)b * DHW + base) = o0;
    *reinterpret_cast<u4*>(s_am + (size_t)b * DHW + base + 1024) = o1;

    __shared__ float redS[4][Cn];
    __shared__ float redM[4][Cn];
#pragma unroll
    for (int c = 0; c < Cn; ++c) {
        float ps = tsum[c], pm = tmax[c];
#pragma unroll
        for (int off = 32; off; off >>= 1) {
            ps += __shfl_xor(ps, off);
            pm = fmaxf(pm, __shfl_xor(pm, off));
        }
        if (lane == 0) { redS[wid][c] = ps; redM[wid][c] = pm; }
    }
    __syncthreads();
    if (threadIdx.x < Cn) {
        const int c = threadIdx.x;
        float s = (redS[0][c] + redS[1][c]) + (redS[2][c] + redS[3][c]);
        float m = fmaxf(fmaxf(redM[0][c], redM[1][c]),
                        fmaxf(redM[2][c], redM[3][c]));
        part_sum[(b * Cn + c) * NCHUNK + chunk] = s;
        part_max[(b * Cn + c) * NCHUNK + chunk] = m;
    }
}

// ============================================================
// Kernel 2: weight-pack + partial-reduce + channel-MLP. 1 block.
// (wpack folded in — no dependency between the two phases; saves a launch)
// ============================================================
__global__ __launch_bounds__(256) void ca_kernel(
    const float* __restrict__ w1, u32* __restrict__ w1h,
    const float* __restrict__ part_sum, const float* __restrict__ part_max,
    const float* __restrict__ fc1_w, const float* __restrict__ fc1_b,
    const float* __restrict__ fc2_w, const float* __restrict__ fc2_b,
    float* __restrict__ ca) {
    const int t = threadIdx.x;
    // ---- weight pack (independent of reduce outputs) ----
    for (int i = t; i < NWH; i += 256) {
        const int oc = i / 343, r = i - oc * 343;
        w1h[i] = packh2(w1[oc * 686 + r], w1[oc * 686 + 343 + r]);
    }

    __shared__ float inpAll[Bn][64];
    __shared__ float h[128];
    {
        const int which = t >> 7;        // 0: sum, 1: max
        const int b = (t >> 5) & 3;
        const int c = t & 31;
        const f4* p4 = reinterpret_cast<const f4*>(
            (which ? part_max : part_sum) + (b * Cn + c) * NCHUNK);
        if (which == 0) {
            float acc = 0.f;
#pragma unroll
            for (int i = 0; i < NCHUNK / 4; ++i) {
                f4 v = p4[i];
                acc += (v.x + v.y) + (v.z + v.w);
            }
            inpAll[b][c] = acc * (1.f / DHW);
        } else {
            float m = -INFINITY;
#pragma unroll
            for (int i = 0; i < NCHUNK / 4; ++i) {
                f4 v = p4[i];
                m = fmaxf(m, fmaxf(fmaxf(v.x, v.y), fmaxf(v.z, v.w)));
            }
            inpAll[b][Cn + c] = m;
        }
    }
    __syncthreads();
#pragma unroll 1
    for (int b = 0; b < Bn; ++b) {
        if (t < 128) {
            float acc = fc1_b[t];
#pragma unroll
            for (int k = 0; k < 64; ++k) acc += fc1_w[t * 64 + k] * inpAll[b][k];
            h[t] = fmaxf(acc, 0.f);
        }
        __syncthreads();
        if (t < Cn) {
            float a2 = fc2_b[t];
#pragma unroll
            for (int k = 0; k < 128; ++k) a2 += fc2_w[t * 128 + k] * h[k];
            ca[b * Cn + t] = 1.f / (1.f + expf(-a2));
        }
        __syncthreads();
    }
}

// ============================================================
// Kernel 3: conv + epilogue — f16 dot2 datapath, TZ=8 tile.
//  Tile 64x*4y*8z, 512 blocks: halo-reads/output 2.5 -> 1.75 u32
//  (DS/CU 19 -> ~13 us, below the 18 us VALU floor); staging passes
//  per CU halved. Halo 39.2 KB (both ics as half2) -> 4 blocks/CU.
//  Epilogue: direct-register NT stores (R6-proven), no sv_s barrier.
// ============================================================
#define TZc 8
#define TYc 4
#define LXc (Wn + 6)   /* 70 */
#define LYc (TYc + 6)  /* 10 */
#define LZc (TZc + 6)  /* 14 */
#define HALO_N (LZc * LYc * LXc)  /* 9800 u32 = 39.2 KB */

__global__ __launch_bounds__(256) void conv_kernel(
    const float* __restrict__ ca_g, const u32* __restrict__ s_am,
    const u32* __restrict__ w1h, const float* __restrict__ w2,
    float* __restrict__ out) {
    __shared__ u32 sIn[HALO_N];               // 39.2 KB, both ics
    __shared__ float ca_s[Cn];

    const int t = threadIdx.x;
    const int bid = blockIdx.x;
    const int b = bid >> 7;            // 128 tiles per batch
    const int tile = bid & 127;
    const int tz = tile >> 4, ty = tile & 15;   // 8 tz x 16 ty
    const int z0 = tz * TZc, y0 = ty * TYc;

    if (t < Cn) ca_s[t] = ca_g[b * Cn + t];

    // ---- single staging pass (both channels at once) ----
    const u32* src = s_am + (size_t)b * DHW;
    for (int i = t; i < HALO_N; i += 256) {
        const int xx = i % LXc;
        const int rem = i / LXc;
        const int yy = rem % LYc;
        const int zz = rem / LYc;
        const int gz = z0 + zz - 3, gy = y0 + yy - 3, gx = xx - 3;
        u32 v = 0u;
        if ((unsigned)gz < (unsigned)Dn && (unsigned)gy < (unsigned)Hn &&
            (unsigned)gx < (unsigned)Wn)
            v = src[(gz * Hn + gy) * Wn + gx];
        sIn[i] = v;
    }
    __syncthreads();

    const int lx = t & 63, ly = t >> 6;

    float a0[TZc] = {0.f, 0.f, 0.f, 0.f, 0.f, 0.f, 0.f, 0.f};
    float a1[TZc] = {0.f, 0.f, 0.f, 0.f, 0.f, 0.f, 0.f, 0.f};
    float a2[TZc] = {0.f, 0.f, 0.f, 0.f, 0.f, 0.f, 0.f, 0.f};
    float a3[TZc] = {0.f, 0.f, 0.f, 0.f, 0.f, 0.f, 0.f, 0.f};

#pragma unroll 1
    for (int kh = 0; kh < 7; ++kh)
#pragma unroll 1
        for (int kw = 0; kw < 7; ++kw) {
            u32 incol[LZc];
#pragma unroll
            for (int s = 0; s < LZc; ++s)
                incol[s] = sIn[(s * LYc + (ly + kh)) * LXc + (lx + kw)];
#pragma unroll
            for (int kd = 0; kd < 7; ++kd) {
                // wave-uniform addresses -> scalar loads
                const int wi = kd * 49 + kh * 7 + kw;
                const u32 w0 = w1h[0 * 343 + wi];
                const u32 w1v = w1h[1 * 343 + wi];
                const u32 w2v = w1h[2 * 343 + wi];
                const u32 w3v = w1h[3 * 343 + wi];
#pragma unroll
                for (int o = 0; o < TZc; ++o) {
                    const u32 iv = incol[o + kd];
                    a0[o] = dot2acc(iv, w0, a0[o]);
                    a1[o] = dot2acc(iv, w1v, a1[o]);
                    a2[o] = dot2acc(iv, w2v, a2[o]);
                    a3[o] = dot2acc(iv, w3v, a3[o]);
                }
            }
        }

    const float c20 = w2[0], c21 = w2[1], c22 = w2[2], c23 = w2[3];
    float sv[TZc];
#pragma unroll
    for (int o = 0; o < TZc; ++o) {
        float s = fmaxf(a0[o], 0.f) * c20 + fmaxf(a1[o], 0.f) * c21 +
                  fmaxf(a2[o], 0.f) * c22 + fmaxf(a3[o], 0.f) * c23;
        sv[o] = 1.f / (1.f + expf(-s));
    }

    // ---- direct-register NT stores: 256B contiguous per wave-inst ----
    const size_t base = (size_t)b * Cn * DHW + (size_t)z0 * HW +
                        (size_t)(y0 + ly) * Wn + lx;
#pragma unroll 1
    for (int c = 0; c < Cn; ++c) {
        const float cav = ca_s[c];
        const size_t cb = base + (size_t)c * DHW;
#pragma unroll
        for (int o = 0; o < TZc; ++o) {
            const float a = sv[o] * cav;
            __builtin_nontemporal_store(a, out + cb + o * HW);
            __builtin_nontemporal_store(1.f - a, out + TOT + cb + o * HW);
        }
    }
}

extern "C" void kernel_launch(void* const* d_in, const int* in_sizes, int n_in,
                              void* d_out, int out_size, void* d_ws,
                              size_t ws_size, hipStream_t stream) {
    const float* x = (const float*)d_in[0];
    const float* fc1_w = (const float*)d_in[1];
    const float* fc1_b = (const float*)d_in[2];
    const float* fc2_w = (const float*)d_in[3];
    const float* fc2_b = (const float*)d_in[4];
    const float* conv1_w = (const float*)d_in[5];
    const float* conv2_w = (const float*)d_in[6];

    float* ws = (float*)d_ws;
    u32* s_am = (u32*)ws;                            // B*DHW u32
    float* part_sum = ws + (size_t)Bn * DHW;         // B*C*NCHUNK
    float* part_max = part_sum + Bn * Cn * NCHUNK;   // B*C*NCHUNK
    float* ca = part_max + Bn * Cn * NCHUNK;         // B*C
    u32* w1h = (u32*)(ca + Bn * Cn);                 // NWH

    reduce_kernel<<<Bn * NCHUNK, 256, 0, stream>>>(x, s_am, part_sum,
                                                   part_max);
    ca_kernel<<<1, 256, 0, stream>>>(conv1_w, w1h, part_sum, part_max, fc1_w,
                                     fc1_b, fc2_w, fc2_b, ca);
    conv_kernel<<<Bn * 128, 256, 0, stream>>>(ca, s_am, w1h, conv2_w,
                                              (float*)d_out);
}

// Round 22
// 139.480 us; speedup vs baseline: 1.0803x; 1.0803x over previous
//
#include <hip/hip_runtime.h>
#include <math.h>

#define Bn 4
#define Cn 32
#define Dn 64
#define Hn 64
#define Wn 64
#define HW (Hn * Wn)
#define DHW (Dn * Hn * Wn)      /* 262144 */
#define TOT (Bn * Cn * DHW)     /* 33554432 */
#define NCHUNK 128              /* spatial chunks per batch in reduce */
#define NWH 1372                /* 4*7*7*7 half2 weights */

typedef float f4 __attribute__((ext_vector_type(4)));
typedef unsigned int u32;
typedef u32 u4 __attribute__((ext_vector_type(4)));
typedef _Float16 h2 __attribute__((ext_vector_type(2)));

__device__ __forceinline__ u32 packh2(float a, float b) {
    h2 h;
    h.x = (_Float16)a;
    h.y = (_Float16)b;
    return __builtin_bit_cast(u32, h);
}
__device__ __forceinline__ h2 uash2(u32 u) { return __builtin_bit_cast(h2, u); }

__device__ __forceinline__ float dot2acc(u32 iv, u32 wv, float acc) {
#if __has_builtin(__builtin_amdgcn_fdot2)
    return __builtin_amdgcn_fdot2(uash2(iv), uash2(wv), acc, false);
#else
    const h2 a = uash2(iv), b = uash2(wv);
    return acc + (float)a.x * (float)b.x + (float)a.y * (float)b.y;
#endif
}

// raw workgroup barrier: waits LDS ops only, leaves NT stores in flight
__device__ __forceinline__ void lds_barrier() {
    asm volatile("s_waitcnt lgkmcnt(0)" ::: "memory");
    __builtin_amdgcn_s_barrier();
}

// ============================================================
// Kernel 1: fused reductions — R20 (measured-good). UNCHANGED.
// ============================================================
__global__ __launch_bounds__(256) void reduce_kernel(
    const float* __restrict__ x, u32* __restrict__ s_am,
    float* __restrict__ part_sum, float* __restrict__ part_max) {
    const int b = blockIdx.x / NCHUNK;
    const int chunk = blockIdx.x % NCHUNK;
    const int base = chunk * 2048 + threadIdx.x * 4;
    const int lane = threadIdx.x & 63;
    const int wid = threadIdx.x >> 6;

    f4 ssum0 = {0.f, 0.f, 0.f, 0.f}, ssum1 = {0.f, 0.f, 0.f, 0.f};
    f4 smax0 = {-INFINITY, -INFINITY, -INFINITY, -INFINITY};
    f4 smax1 = smax0;
    float tsum[Cn], tmax[Cn];

    const float* xp = x + (size_t)b * Cn * DHW + base;
#pragma unroll
    for (int c = 0; c < Cn; ++c) {
        const f4 v0 = *reinterpret_cast<const f4*>(xp + (size_t)c * DHW);
        const f4 v1 = *reinterpret_cast<const f4*>(xp + (size_t)c * DHW + 1024);
        ssum0 += v0; ssum1 += v1;
        smax0.x = fmaxf(smax0.x, v0.x); smax0.y = fmaxf(smax0.y, v0.y);
        smax0.z = fmaxf(smax0.z, v0.z); smax0.w = fmaxf(smax0.w, v0.w);
        smax1.x = fmaxf(smax1.x, v1.x); smax1.y = fmaxf(smax1.y, v1.y);
        smax1.z = fmaxf(smax1.z, v1.z); smax1.w = fmaxf(smax1.w, v1.w);
        const float s0 = (v0.x + v0.y) + (v0.z + v0.w);
        const float s1 = (v1.x + v1.y) + (v1.z + v1.w);
        tsum[c] = s0 + s1;
        const float m0 = fmaxf(fmaxf(v0.x, v0.y), fmaxf(v0.z, v0.w));
        const float m1 = fmaxf(fmaxf(v1.x, v1.y), fmaxf(v1.z, v1.w));
        tmax[c] = fmaxf(m0, m1);
    }

    const f4 av0 = ssum0 * (1.f / Cn);
    const f4 av1 = ssum1 * (1.f / Cn);
    u4 o0 = {packh2(av0.x, smax0.x), packh2(av0.y, smax0.y),
             packh2(av0.z, smax0.z), packh2(av0.w, smax0.w)};
    u4 o1 = {packh2(av1.x, smax1.x), packh2(av1.y, smax1.y),
             packh2(av1.z, smax1.z), packh2(av1.w, smax1.w)};
    *reinterpret_cast<u4*>(s_am + (size_t)b * DHW + base) = o0;
    *reinterpret_cast<u4*>(s_am + (size_t)b * DHW + base + 1024) = o1;

    __shared__ float redS[4][Cn];
    __shared__ float redM[4][Cn];
#pragma unroll
    for (int c = 0; c < Cn; ++c) {
        float ps = tsum[c], pm = tmax[c];
#pragma unroll
        for (int off = 32; off; off >>= 1) {
            ps += __shfl_xor(ps, off);
            pm = fmaxf(pm, __shfl_xor(pm, off));
        }
        if (lane == 0) { redS[wid][c] = ps; redM[wid][c] = pm; }
    }
    __syncthreads();
    if (threadIdx.x < Cn) {
        const int c = threadIdx.x;
        float s = (redS[0][c] + redS[1][c]) + (redS[2][c] + redS[3][c]);
        float m = fmaxf(fmaxf(redM[0][c], redM[1][c]),
                        fmaxf(redM[2][c], redM[3][c]));
        part_sum[(b * Cn + c) * NCHUNK + chunk] = s;
        part_max[(b * Cn + c) * NCHUNK + chunk] = m;
    }
}

// ============================================================
// Kernel 2: weight-pack + partial-reduce + channel-MLP. UNCHANGED (R21).
// ============================================================
__global__ __launch_bounds__(256) void ca_kernel(
    const float* __restrict__ w1, u32* __restrict__ w1h,
    const float* __restrict__ part_sum, const float* __restrict__ part_max,
    const float* __restrict__ fc1_w, const float* __restrict__ fc1_b,
    const float* __restrict__ fc2_w, const float* __restrict__ fc2_b,
    float* __restrict__ ca) {
    const int t = threadIdx.x;
    for (int i = t; i < NWH; i += 256) {
        const int oc = i / 343, r = i - oc * 343;
        w1h[i] = packh2(w1[oc * 686 + r], w1[oc * 686 + 343 + r]);
    }

    __shared__ float inpAll[Bn][64];
    __shared__ float h[128];
    {
        const int which = t >> 7;        // 0: sum, 1: max
        const int b = (t >> 5) & 3;
        const int c = t & 31;
        const f4* p4 = reinterpret_cast<const f4*>(
            (which ? part_max : part_sum) + (b * Cn + c) * NCHUNK);
        if (which == 0) {
            float acc = 0.f;
#pragma unroll
            for (int i = 0; i < NCHUNK / 4; ++i) {
                f4 v = p4[i];
                acc += (v.x + v.y) + (v.z + v.w);
            }
            inpAll[b][c] = acc * (1.f / DHW);
        } else {
            float m = -INFINITY;
#pragma unroll
            for (int i = 0; i < NCHUNK / 4; ++i) {
                f4 v = p4[i];
                m = fmaxf(m, fmaxf(fmaxf(v.x, v.y), fmaxf(v.z, v.w)));
            }
            inpAll[b][Cn + c] = m;
        }
    }
    __syncthreads();
#pragma unroll 1
    for (int b = 0; b < Bn; ++b) {
        if (t < 128) {
            float acc = fc1_b[t];
#pragma unroll
            for (int k = 0; k < 64; ++k) acc += fc1_w[t * 64 + k] * inpAll[b][k];
            h[t] = fmaxf(acc, 0.f);
        }
        __syncthreads();
        if (t < Cn) {
            float a2 = fc2_b[t];
#pragma unroll
            for (int k = 0; k < 128; ++k) a2 += fc2_w[t * 128 + k] * h[k];
            ca[b * Cn + t] = 1.f / (1.f + expf(-a2));
        }
        __syncthreads();
    }
}

// ============================================================
// Kernel 3: conv + epilogue — f16 dot2 (R20 datapath), TWO half-tiles
// per block with vmcnt-preserving raw barriers:
//  tile 64x*2y*4z; block does tiles (tz,tyh) then (tz,tyh+16).
//  Between phases: lgkmcnt(0)+s_barrier ONLY — tile-A's NT stores stay
//  in flight and drain under tile-B's stage+compute (T3/T4 pattern).
//  LDS 24.6 KB -> 4 blocks/CU (16 waves), 1024 blocks.
//  Epilogue: sv_s staged, f4 stores (R20-proven granule; 512B runs).
// ============================================================
#define TZc 4
#define TYc 2
#define LXc (Wn + 6)   /* 70 */
#define LYc (TYc + 6)  /* 8  */
#define LZc (TZc + 6)  /* 10 */
#define HALO_N (LZc * LYc * LXc)  /* 5600 u32 = 22.4 KB */

__global__ __launch_bounds__(256) void conv_kernel(
    const float* __restrict__ ca_g, const u32* __restrict__ s_am,
    const u32* __restrict__ w1h, const float* __restrict__ w2,
    float* __restrict__ out) {
    __shared__ u32 sIn[HALO_N];                   // 22.4 KB, both ics
    __shared__ float sv_s[TZc * TYc * Wn];        // 512 floats, 2 KB
    __shared__ float ca_s[Cn];

    const int t = threadIdx.x;
    const int bid = blockIdx.x;
    const int b = bid >> 8;             // 256 pairs per batch
    const int pair = bid & 255;
    const int tz = pair >> 4, tyh = pair & 15;   // 16 tz x 16 tyh
    const int z0 = tz * TZc;

    if (t < Cn) ca_s[t] = ca_g[b * Cn + t];

    const u32* src = s_am + (size_t)b * DHW;
    const int lx = t & 63, ly = (t >> 6) & 1, zh = t >> 7;  // 64 x 2 x 2
    const float c20 = w2[0], c21 = w2[1], c22 = w2[2], c23 = w2[3];

#pragma unroll 1
    for (int half = 0; half < 2; ++half) {
        const int y0 = (tyh + half * 16) * TYc;

        // ---- stage halo (raw barrier: vmcnt NOT drained) ----
        lds_barrier();   // protects sIn/sv_s reuse (half 1); harmless half 0
        for (int i = t; i < HALO_N; i += 256) {
            const int xx = i % LXc;
            const int rem = i / LXc;
            const int yy = rem % LYc;
            const int zz = rem / LYc;
            const int gz = z0 + zz - 3, gy = y0 + yy - 3, gx = xx - 3;
            u32 v = 0u;
            if ((unsigned)gz < (unsigned)Dn && (unsigned)gy < (unsigned)Hn &&
                (unsigned)gx < (unsigned)Wn)
                v = src[(gz * Hn + gy) * Wn + gx];
            sIn[i] = v;
        }
        lds_barrier();

        // ---- compute: thread owns 2-z column of (lx, ly) ----
        float a0[2] = {0.f, 0.f}, a1[2] = {0.f, 0.f};
        float a2[2] = {0.f, 0.f}, a3[2] = {0.f, 0.f};
#pragma unroll 1
        for (int kh = 0; kh < 7; ++kh)
#pragma unroll 1
            for (int kw = 0; kw < 7; ++kw) {
                u32 incol[8];
#pragma unroll
                for (int s = 0; s < 8; ++s)
                    incol[s] = sIn[((zh * 2 + s) * LYc + (ly + kh)) * LXc +
                                   (lx + kw)];
#pragma unroll
                for (int kd = 0; kd < 7; ++kd) {
                    // wave-uniform addresses -> scalar loads
                    const int wi = kd * 49 + kh * 7 + kw;
                    const u32 w0 = w1h[0 * 343 + wi];
                    const u32 w1v = w1h[1 * 343 + wi];
                    const u32 w2v = w1h[2 * 343 + wi];
                    const u32 w3v = w1h[3 * 343 + wi];
#pragma unroll
                    for (int o = 0; o < 2; ++o) {
                        const u32 iv = incol[o + kd];
                        a0[o] = dot2acc(iv, w0, a0[o]);
                        a1[o] = dot2acc(iv, w1v, a1[o]);
                        a2[o] = dot2acc(iv, w2v, a2[o]);
                        a3[o] = dot2acc(iv, w3v, a3[o]);
                    }
                }
            }

#pragma unroll
        for (int o = 0; o < 2; ++o) {
            const int oz = zh * 2 + o;
            float s = fmaxf(a0[o], 0.f) * c20 + fmaxf(a1[o], 0.f) * c21 +
                      fmaxf(a2[o], 0.f) * c22 + fmaxf(a3[o], 0.f) * c23;
            sv_s[(oz * TYc + ly) * Wn + lx] = 1.f / (1.f + expf(-s));
        }
        lds_barrier();

        // ---- epilogue: f4 NT stores; two 512B runs per wave-inst ----
        const int wv = t >> 6, ln = t & 63;
        const int ozh = ln >> 5, lncol = ln & 31;
        const f4* sv4 = reinterpret_cast<const f4*>(sv_s);
        f4* out4 = reinterpret_cast<f4*>(out);
        const size_t totq4 = TOT / 4;
#pragma unroll 1
        for (int combo = wv; combo < Cn * 2; combo += 4) {
            const int c = combo >> 1, zp = combo & 1;
            const int oz = zp * 2 + ozh;
            const float cav = ca_s[c];
            const f4 v = sv4[oz * (TYc * Wn / 4) + lncol];
            const f4 att = v * cav;
            const f4 anti = 1.f - att;
            const size_t off = (((size_t)(b * Cn + c) * DHW) >> 2) +
                               (size_t)(z0 + oz) * (HW / 4) +
                               (size_t)y0 * (Wn / 4) + lncol;
            __builtin_nontemporal_store(att, &out4[off]);
            __builtin_nontemporal_store(anti, &out4[totq4 + off]);
        }
    }
}

extern "C" void kernel_launch(void* const* d_in, const int* in_sizes, int n_in,
                              void* d_out, int out_size, void* d_ws,
                              size_t ws_size, hipStream_t stream) {
    const float* x = (const float*)d_in[0];
    const float* fc1_w = (const float*)d_in[1];
    const float* fc1_b = (const float*)d_in[2];
    const float* fc2_w = (const float*)d_in[3];
    const float* fc2_b = (const float*)d_in[4];
    const float* conv1_w = (const float*)d_in[5];
    const float* conv2_w = (const float*)d_in[6];

    float* ws = (float*)d_ws;
    u32* s_am = (u32*)ws;                            // B*DHW u32
    float* part_sum = ws + (size_t)Bn * DHW;         // B*C*NCHUNK
    float* part_max = part_sum + Bn * Cn * NCHUNK;   // B*C*NCHUNK
    float* ca = part_max + Bn * Cn * NCHUNK;         // B*C
    u32* w1h = (u32*)(ca + Bn * Cn);                 // NWH

    reduce_kernel<<<Bn * NCHUNK, 256, 0, stream>>>(x, s_am, part_sum,
                                                   part_max);
    ca_kernel<<<1, 256, 0, stream>>>(conv1_w, w1h, part_sum, part_max, fc1_w,
                                     fc1_b, fc2_w, fc2_b, ca);
    conv_kernel<<<Bn * 256, 256, 0, stream>>>(ca, s_am, w1h, conv2_w,
                                              (float*)d_out);
}

// Round 23
// 130.958 us; speedup vs baseline: 1.1506x; 1.0651x over previous
//
#include <hip/hip_runtime.h>
#include <math.h>

#define Bn 4
#define Cn 32
#define Dn 64
#define Hn 64
#define Wn 64
#define HW (Hn * Wn)
#define DHW (Dn * Hn * Wn)      /* 262144 */
#define TOT (Bn * Cn * DHW)     /* 33554432 */
#define NCHUNK 128              /* spatial chunks per batch in reduce */
#define NWH 1372                /* 4*7*7*7 half2 weights */

typedef float f4 __attribute__((ext_vector_type(4)));
typedef unsigned int u32;
typedef u32 u4 __attribute__((ext_vector_type(4)));
typedef _Float16 h2 __attribute__((ext_vector_type(2)));

__device__ __forceinline__ u32 packh2(float a, float b) {
    h2 h;
    h.x = (_Float16)a;
    h.y = (_Float16)b;
    return __builtin_bit_cast(u32, h);
}
__device__ __forceinline__ h2 uash2(u32 u) { return __builtin_bit_cast(h2, u); }

__device__ __forceinline__ float dot2acc(u32 iv, u32 wv, float acc) {
#if __has_builtin(__builtin_amdgcn_fdot2)
    return __builtin_amdgcn_fdot2(uash2(iv), uash2(wv), acc, false);
#else
    const h2 a = uash2(iv), b = uash2(wv);
    return acc + (float)a.x * (float)b.x + (float)a.y * (float)b.y;
#endif
}

// ============================================================
// Kernel 1: fused reductions (R20, measured-best).
// Spatial stats stored as interleaved half2(avg,max); partials fp32.
// ============================================================
__global__ __launch_bounds__(256) void reduce_kernel(
    const float* __restrict__ x, u32* __restrict__ s_am,
    float* __restrict__ part_sum, float* __restrict__ part_max) {
    const int b = blockIdx.x / NCHUNK;
    const int chunk = blockIdx.x % NCHUNK;
    const int base = chunk * 2048 + threadIdx.x * 4;
    const int lane = threadIdx.x & 63;
    const int wid = threadIdx.x >> 6;

    f4 ssum0 = {0.f, 0.f, 0.f, 0.f}, ssum1 = {0.f, 0.f, 0.f, 0.f};
    f4 smax0 = {-INFINITY, -INFINITY, -INFINITY, -INFINITY};
    f4 smax1 = smax0;
    float tsum[Cn], tmax[Cn];

    const float* xp = x + (size_t)b * Cn * DHW + base;
#pragma unroll
    for (int c = 0; c < Cn; ++c) {
        const f4 v0 = *reinterpret_cast<const f4*>(xp + (size_t)c * DHW);
        const f4 v1 = *reinterpret_cast<const f4*>(xp + (size_t)c * DHW + 1024);
        ssum0 += v0; ssum1 += v1;
        smax0.x = fmaxf(smax0.x, v0.x); smax0.y = fmaxf(smax0.y, v0.y);
        smax0.z = fmaxf(smax0.z, v0.z); smax0.w = fmaxf(smax0.w, v0.w);
        smax1.x = fmaxf(smax1.x, v1.x); smax1.y = fmaxf(smax1.y, v1.y);
        smax1.z = fmaxf(smax1.z, v1.z); smax1.w = fmaxf(smax1.w, v1.w);
        const float s0 = (v0.x + v0.y) + (v0.z + v0.w);
        const float s1 = (v1.x + v1.y) + (v1.z + v1.w);
        tsum[c] = s0 + s1;
        const float m0 = fmaxf(fmaxf(v0.x, v0.y), fmaxf(v0.z, v0.w));
        const float m1 = fmaxf(fmaxf(v1.x, v1.y), fmaxf(v1.z, v1.w));
        tmax[c] = fmaxf(m0, m1);
    }

    const f4 av0 = ssum0 * (1.f / Cn);
    const f4 av1 = ssum1 * (1.f / Cn);
    u4 o0 = {packh2(av0.x, smax0.x), packh2(av0.y, smax0.y),
             packh2(av0.z, smax0.z), packh2(av0.w, smax0.w)};
    u4 o1 = {packh2(av1.x, smax1.x), packh2(av1.y, smax1.y),
             packh2(av1.z, smax1.z), packh2(av1.w, smax1.w)};
    *reinterpret_cast<u4*>(s_am + (size_t)b * DHW + base) = o0;
    *reinterpret_cast<u4*>(s_am + (size_t)b * DHW + base + 1024) = o1;

    __shared__ float redS[4][Cn];
    __shared__ float redM[4][Cn];
#pragma unroll
    for (int c = 0; c < Cn; ++c) {
        float ps = tsum[c], pm = tmax[c];
#pragma unroll
        for (int off = 32; off; off >>= 1) {
            ps += __shfl_xor(ps, off);
            pm = fmaxf(pm, __shfl_xor(pm, off));
        }
        if (lane == 0) { redS[wid][c] = ps; redM[wid][c] = pm; }
    }
    __syncthreads();
    if (threadIdx.x < Cn) {
        const int c = threadIdx.x;
        float s = (redS[0][c] + redS[1][c]) + (redS[2][c] + redS[3][c]);
        float m = fmaxf(fmaxf(redM[0][c], redM[1][c]),
                        fmaxf(redM[2][c], redM[3][c]));
        part_sum[(b * Cn + c) * NCHUNK + chunk] = s;
        part_max[(b * Cn + c) * NCHUNK + chunk] = m;
    }
}

// ============================================================
// Kernel 2: weight-pack + partial-reduce + channel-MLP. 1 block.
// ============================================================
__global__ __launch_bounds__(256) void ca_kernel(
    const float* __restrict__ w1, u32* __restrict__ w1h,
    const float* __restrict__ part_sum, const float* __restrict__ part_max,
    const float* __restrict__ fc1_w, const float* __restrict__ fc1_b,
    const float* __restrict__ fc2_w, const float* __restrict__ fc2_b,
    float* __restrict__ ca) {
    const int t = threadIdx.x;
    // ---- weight pack (independent of reduce outputs) ----
    for (int i = t; i < NWH; i += 256) {
        const int oc = i / 343, r = i - oc * 343;
        w1h[i] = packh2(w1[oc * 686 + r], w1[oc * 686 + 343 + r]);
    }

    __shared__ float inpAll[Bn][64];
    __shared__ float h[128];
    {
        const int which = t >> 7;        // 0: sum, 1: max
        const int b = (t >> 5) & 3;
        const int c = t & 31;
        const f4* p4 = reinterpret_cast<const f4*>(
            (which ? part_max : part_sum) + (b * Cn + c) * NCHUNK);
        if (which == 0) {
            float acc = 0.f;
#pragma unroll
            for (int i = 0; i < NCHUNK / 4; ++i) {
                f4 v = p4[i];
                acc += (v.x + v.y) + (v.z + v.w);
            }
            inpAll[b][c] = acc * (1.f / DHW);
        } else {
            float m = -INFINITY;
#pragma unroll
            for (int i = 0; i < NCHUNK / 4; ++i) {
                f4 v = p4[i];
                m = fmaxf(m, fmaxf(fmaxf(v.x, v.y), fmaxf(v.z, v.w)));
            }
            inpAll[b][Cn + c] = m;
        }
    }
    __syncthreads();
#pragma unroll 1
    for (int b = 0; b < Bn; ++b) {
        if (t < 128) {
            float acc = fc1_b[t];
#pragma unroll
            for (int k = 0; k < 64; ++k) acc += fc1_w[t * 64 + k] * inpAll[b][k];
            h[t] = fmaxf(acc, 0.f);
        }
        __syncthreads();
        if (t < Cn) {
            float a2 = fc2_b[t];
#pragma unroll
            for (int k = 0; k < 128; ++k) a2 += fc2_w[t * 128 + k] * h[k];
            ca[b * Cn + t] = 1.f / (1.f + expf(-a2));
        }
        __syncthreads();
    }
}

// ============================================================
// Kernel 3: conv + epilogue — f16 dot2 datapath (R20, measured-best).
//  Tile 64x*4y*4z, 1024 blocks, halo 28 KB (both ics as half2),
//  4 blocks/CU. Wave-uniform scalar weight loads. sv_s-staged f4 NT
//  epilogue (1KB contiguous runs per wave-inst) — load-bearing (R21).
// ============================================================
#define TZc 4
#define TYc 4
#define LXc (Wn + 6)   /* 70 */
#define LYc (TYc + 6)  /* 10 */
#define LZc (TZc + 6)  /* 10 */
#define HALO_N (LZc * LYc * LXc)  /* 7000 u32 = 28 KB */

__global__ __launch_bounds__(256) void conv_kernel(
    const float* __restrict__ ca_g, const u32* __restrict__ s_am,
    const u32* __restrict__ w1h, const float* __restrict__ w2,
    float* __restrict__ out) {
    __shared__ u32 sIn[HALO_N];               // 28 KB, both ics
    __shared__ float sv_s[TZc * TYc * Wn];    // 4 KB
    __shared__ float ca_s[Cn];

    const int t = threadIdx.x;
    const int bid = blockIdx.x;
    const int b = bid >> 8;            // 256 tiles per batch
    const int tile = bid & 255;
    const int tz = tile >> 4, ty = tile & 15;
    const int z0 = tz * TZc, y0 = ty * TYc;

    if (t < Cn) ca_s[t] = ca_g[b * Cn + t];

    // ---- single staging pass (both channels at once) ----
    const u32* src = s_am + (size_t)b * DHW;
    for (int i = t; i < HALO_N; i += 256) {
        const int xx = i % LXc;
        const int rem = i / LXc;
        const int yy = rem % LYc;
        const int zz = rem / LYc;
        const int gz = z0 + zz - 3, gy = y0 + yy - 3, gx = xx - 3;
        u32 v = 0u;
        if ((unsigned)gz < (unsigned)Dn && (unsigned)gy < (unsigned)Hn &&
            (unsigned)gx < (unsigned)Wn)
            v = src[(gz * Hn + gy) * Wn + gx];
        sIn[i] = v;
    }
    __syncthreads();

    const int lx = t & 63, ly = t >> 6;

    float a0[TZc] = {0.f, 0.f, 0.f, 0.f};
    float a1[TZc] = {0.f, 0.f, 0.f, 0.f};
    float a2[TZc] = {0.f, 0.f, 0.f, 0.f};
    float a3[TZc] = {0.f, 0.f, 0.f, 0.f};

#pragma unroll 1
    for (int kh = 0; kh < 7; ++kh)
#pragma unroll 1
        for (int kw = 0; kw < 7; ++kw) {
            u32 incol[LZc];
#pragma unroll
            for (int s = 0; s < LZc; ++s)
                incol[s] = sIn[(s * LYc + (ly + kh)) * LXc + (lx + kw)];
#pragma unroll
            for (int kd = 0; kd < 7; ++kd) {
                // wave-uniform addresses -> scalar loads
                const int wi = kd * 49 + kh * 7 + kw;
                const u32 w0 = w1h[0 * 343 + wi];
                const u32 w1v = w1h[1 * 343 + wi];
                const u32 w2v = w1h[2 * 343 + wi];
                const u32 w3v = w1h[3 * 343 + wi];
#pragma unroll
                for (int o = 0; o < TZc; ++o) {
                    const u32 iv = incol[o + kd];
                    a0[o] = dot2acc(iv, w0, a0[o]);
                    a1[o] = dot2acc(iv, w1v, a1[o]);
                    a2[o] = dot2acc(iv, w2v, a2[o]);
                    a3[o] = dot2acc(iv, w3v, a3[o]);
                }
            }
        }

    const float c20 = w2[0], c21 = w2[1], c22 = w2[2], c23 = w2[3];
#pragma unroll
    for (int o = 0; o < TZc; ++o) {
        float s = fmaxf(a0[o], 0.f) * c20 + fmaxf(a1[o], 0.f) * c21 +
                  fmaxf(a2[o], 0.f) * c22 + fmaxf(a3[o], 0.f) * c23;
        sv_s[(o * TYc + ly) * Wn + lx] = 1.f / (1.f + expf(-s));
    }
    __syncthreads();

    // ---- epilogue: per combo a wave writes 1KB contiguous per stream ----
    const int wv = t >> 6, ln = t & 63;
    const f4* sv4 = reinterpret_cast<const f4*>(sv_s);
    f4* out4 = reinterpret_cast<f4*>(out);
    const size_t totq4 = TOT / 4;
#pragma unroll 1
    for (int combo = wv; combo < Cn * TZc; combo += 4) {
        const int c = combo >> 2, oz = combo & 3;
        const float cav = ca_s[c];
        const f4 v = sv4[oz * 64 + ln];
        const f4 att = v * cav;
        const f4 anti = 1.f - att;
        const size_t off = (((size_t)(b * Cn + c) * DHW) >> 2) +
                           (size_t)(z0 + oz) * (HW / 4) +
                           (size_t)y0 * (Wn / 4) + ln;
        __builtin_nontemporal_store(att, &out4[off]);
        __builtin_nontemporal_store(anti, &out4[totq4 + off]);
    }
}

extern "C" void kernel_launch(void* const* d_in, const int* in_sizes, int n_in,
                              void* d_out, int out_size, void* d_ws,
                              size_t ws_size, hipStream_t stream) {
    const float* x = (const float*)d_in[0];
    const float* fc1_w = (const float*)d_in[1];
    const float* fc1_b = (const float*)d_in[2];
    const float* fc2_w = (const float*)d_in[3];
    const float* fc2_b = (const float*)d_in[4];
    const float* conv1_w = (const float*)d_in[5];
    const float* conv2_w = (const float*)d_in[6];

    float* ws = (float*)d_ws;
    u32* s_am = (u32*)ws;                            // B*DHW u32
    float* part_sum = ws + (size_t)Bn * DHW;         // B*C*NCHUNK
    float* part_max = part_sum + Bn * Cn * NCHUNK;   // B*C*NCHUNK
    float* ca = part_max + Bn * Cn * NCHUNK;         // B*C
    u32* w1h = (u32*)(ca + Bn * Cn);                 // NWH

    reduce_kernel<<<Bn * NCHUNK, 256, 0, stream>>>(x, s_am, part_sum,
                                                   part_max);
    ca_kernel<<<1, 256, 0, stream>>>(conv1_w, w1h, part_sum, part_max, fc1_w,
                                     fc1_b, fc2_w, fc2_b, ca);
    conv_kernel<<<Bn * 256, 256, 0, stream>>>(ca, s_am, w1h, conv2_w,
                                              (float*)d_out);
}